// Round 3
// baseline (869.487 us; speedup 1.0000x reference)
//
#include <hip/hip_runtime.h>
#include <math.h>

// Problem constants (match reference)
constexpr int N   = 16384;
constexpr int E   = 393216;
constexpr int EF  = E + N;     // edges + self loops
constexpr int G   = 256;
constexpr int HID = 128;

// ---------------------------------------------------------------------------
// 16-lane (DPP row) all-lanes sum via row_ror 1,2,4,8 — pure VALU
// ---------------------------------------------------------------------------
__device__ __forceinline__ float red16(float x) {
    union fi { float f; int i; };
    fi a, b;
    a.f = x;
    b.i = __builtin_amdgcn_mov_dpp(a.i, 0x121, 0xf, 0xf, false); a.f += b.f;
    b.i = __builtin_amdgcn_mov_dpp(a.i, 0x122, 0xf, 0xf, false); a.f += b.f;
    b.i = __builtin_amdgcn_mov_dpp(a.i, 0x124, 0xf, 0xf, false); a.f += b.f;
    b.i = __builtin_amdgcn_mov_dpp(a.i, 0x128, 0xf, 0xf, false); a.f += b.f;
    return a.f;
}

// ---------------------------------------------------------------------------
// Preprocessing: CSR by destination.  k_hist also accumulates per-target
// edge_attr sums (for the self-loop fill_value='mean').
// ---------------------------------------------------------------------------
__global__ __launch_bounds__(256) void k_hist(const int* __restrict__ dst,
                                              const float* __restrict__ edge_attr,
                                              int* __restrict__ cnt,
                                              float* __restrict__ loopsum) {
    int e = blockIdx.x * 256 + threadIdx.x;
    if (e >= E) return;
    int d = dst[e];
    atomicAdd(&cnt[d], 1);
#pragma unroll
    for (int q = 0; q < 6; q++)
        atomicAdd(&loopsum[d * 6 + q], edge_attr[e * 6 + q]);
}

// single-block inclusive scan over N=16384 = 1024*16 counts (+1 self loop each)
__global__ __launch_bounds__(1024) void k_scan(const int* __restrict__ cnt,
                                               int* __restrict__ row_ptr) {
    __shared__ int lds[1024];
    int t = threadIdx.x;
    int local[16];
    int s = 0;
    int base = t * 16;
#pragma unroll
    for (int q = 0; q < 16; q++) { local[q] = cnt[base + q] + 1; s += local[q]; }
    lds[t] = s;
    __syncthreads();
    for (int off = 1; off < 1024; off <<= 1) {
        int v = (t >= off) ? lds[t - off] : 0;
        __syncthreads();
        lds[t] += v;
        __syncthreads();
    }
    int run = (t == 0) ? 0 : lds[t - 1];
    if (t == 0) row_ptr[0] = 0;
#pragma unroll
    for (int q = 0; q < 16; q++) { run += local[q]; row_ptr[base + q + 1] = run; }
}

__global__ __launch_bounds__(256) void k_scatter(const int* __restrict__ src,
                                                 const int* __restrict__ dst,
                                                 const int* __restrict__ row_ptr,
                                                 int* __restrict__ fill,
                                                 int* __restrict__ csr_src,
                                                 int* __restrict__ csr_eid) {
    int e = blockIdx.x * 256 + threadIdx.x;
    if (e >= E) return;
    int d = dst[e];
    int pos = row_ptr[d] + atomicAdd(&fill[d], 1);
    csr_src[pos] = src[e];
    csr_eid[pos] = e;
}

__global__ __launch_bounds__(256) void k_selfloop(const int* __restrict__ row_ptr,
                                                  int* __restrict__ csr_src,
                                                  int* __restrict__ csr_eid) {
    int i = blockIdx.x * 256 + threadIdx.x;
    if (i >= N) return;
    int pos = row_ptr[i + 1] - 1;   // last slot of row i is the self loop
    csr_src[pos] = i;
    csr_eid[pos] = E + i;
}

// Gather edge_attr into CSR slot order, pad to 8; self-loop slots get the
// per-target mean computed from loopsum / (deg) .
__global__ __launch_bounds__(256) void k_build_ea(const int* __restrict__ csr_eid,
                                                  const int* __restrict__ row_ptr,
                                                  const float* __restrict__ edge_attr,
                                                  const float* __restrict__ loopsum,
                                                  float* __restrict__ csr_ea) {
    int p = blockIdx.x * 256 + threadIdx.x;
    if (p >= EF) return;
    int eid = csr_eid[p];
    float4 a, b;
    if (eid < E) {
        const float* s = edge_attr + (size_t)eid * 6;
        a = {s[0], s[1], s[2], s[3]};
        b = {s[4], s[5], 0.0f, 0.0f};
    } else {
        int i = eid - E;
        float deg = (float)(row_ptr[i + 1] - row_ptr[i] - 1);
        float inv = 1.0f / fmaxf(deg, 1.0f);
        const float* s = loopsum + (size_t)i * 6;
        a = {s[0] * inv, s[1] * inv, s[2] * inv, s[3] * inv};
        b = {s[4] * inv, s[5] * inv, 0.0f, 0.0f};
    }
    float4* dst = (float4*)(csr_ea + (size_t)p * 8);
    dst[0] = a;
    dst[1] = b;
}

// ---------------------------------------------------------------------------
// Input projection: h = relu(x @ Win + b_in), x is (N,21)
// ---------------------------------------------------------------------------
__global__ __launch_bounds__(128) void k_ingemm(const float* __restrict__ x,
                                                const float* __restrict__ Win,
                                                const float* __restrict__ b_in,
                                                float* __restrict__ h) {
    __shared__ float xs[21];
    int i = blockIdx.x;
    int c = threadIdx.x;
    if (c < 21) xs[c] = x[i * 21 + c];
    __syncthreads();
    float acc = b_in[c];
#pragma unroll
    for (int d = 0; d < 21; d++) acc += xs[d] * Win[d * HID + c];
    h[i * HID + c] = fmaxf(acc, 0.0f);
}

// ---------------------------------------------------------------------------
// Per-layer projections: XL = h@Wl + bl, XR = h@Wr + br
// 16-row tile per block; thread owns (matrix, col-pair, 8 rows).
// If bns != nullptr the input is GOUT of the previous (even) layer and
// relu(BN(.)) is applied on the fly during the tile load.
// ---------------------------------------------------------------------------
__global__ __launch_bounds__(256) void k_gemm_lr(const float* __restrict__ h,
                                                 const float* __restrict__ bns,
                                                 const float* __restrict__ gamma,
                                                 const float* __restrict__ beta,
                                                 const float* __restrict__ Wl,
                                                 const float* __restrict__ bl,
                                                 const float* __restrict__ Wr,
                                                 const float* __restrict__ br,
                                                 float* __restrict__ XL,
                                                 float* __restrict__ XR) {
    __shared__ float hs[16][HID];
    __shared__ float sc[HID], sh[HID];
    int t = threadIdx.x;
    int r0 = blockIdx.x * 16;
    if (bns) {
        if (t < 128) {
            const float invN = 1.0f / (float)N;
            float mean = bns[t] * invN;
            float var  = bns[128 + t] * invN - mean * mean;
            float inv  = rsqrtf(var + 1e-5f);
            float s = gamma[t] * inv;
            sc[t] = s;
            sh[t] = beta[t] - mean * s;
        }
        __syncthreads();
    }
    {
        int row = t >> 4;
        int col = (t & 15) * 8;
        const float4* src = (const float4*)&h[(size_t)(r0 + row) * HID + col];
        float4 a = src[0];
        float4 b = src[1];
        if (bns) {
            float4 s0 = *(const float4*)&sc[col];
            float4 s1 = *(const float4*)&sc[col + 4];
            float4 h0 = *(const float4*)&sh[col];
            float4 h1 = *(const float4*)&sh[col + 4];
            a.x = fmaxf(fmaf(a.x, s0.x, h0.x), 0.0f);
            a.y = fmaxf(fmaf(a.y, s0.y, h0.y), 0.0f);
            a.z = fmaxf(fmaf(a.z, s0.z, h0.z), 0.0f);
            a.w = fmaxf(fmaf(a.w, s0.w, h0.w), 0.0f);
            b.x = fmaxf(fmaf(b.x, s1.x, h1.x), 0.0f);
            b.y = fmaxf(fmaf(b.y, s1.y, h1.y), 0.0f);
            b.z = fmaxf(fmaf(b.z, s1.z, h1.z), 0.0f);
            b.w = fmaxf(fmaf(b.w, s1.w, h1.w), 0.0f);
        }
        float4* dst = (float4*)&hs[row][col];
        dst[0] = a;
        dst[1] = b;
    }
    __syncthreads();
    bool right = t >= 128;
    int cp = (t & 63) * 2;
    int rbase = ((t >> 6) & 1) * 8;
    const float* W    = right ? Wr : Wl;
    const float* bias = right ? br : bl;
    float* OUT        = right ? XR : XL;
    float b0 = bias[cp], b1 = bias[cp + 1];
    float acc0[8], acc1[8];
#pragma unroll
    for (int r = 0; r < 8; r++) { acc0[r] = b0; acc1[r] = b1; }
    for (int k = 0; k < HID; k += 4) {
        float4 h4[8];
#pragma unroll
        for (int r = 0; r < 8; r++) h4[r] = *(const float4*)&hs[rbase + r][k];
#pragma unroll
        for (int kk = 0; kk < 4; kk++) {
            float2 w = *(const float2*)&W[(size_t)(k + kk) * HID + cp];
#pragma unroll
            for (int r = 0; r < 8; r++) {
                float hv = ((const float*)&h4[r])[kk];
                acc0[r] = fmaf(hv, w.x, acc0[r]);
                acc1[r] = fmaf(hv, w.y, acc1[r]);
            }
        }
    }
#pragma unroll
    for (int r = 0; r < 8; r++) {
        float2 o = {acc0[r], acc1[r]};
        *(float2*)&OUT[(size_t)(r0 + rbase + r) * HID + cp] = o;
    }
}

// ---------------------------------------------------------------------------
// Edge kernel: one wave per node. Lane = head*16 + s; owns channels
// (h*32+2s, h*32+2s+1). 4-step DPP row reduction for the attention dot;
// 4-edge-batched online softmax, xl gathers prefetched one chunk ahead.
// ---------------------------------------------------------------------------
__device__ __forceinline__ void pf_xl(int e, int e1,
                                      const int* __restrict__ csr_src,
                                      const float* __restrict__ xl, int ch0,
                                      float2 out[4]) {
#pragma unroll
    for (int k = 0; k < 4; k++) {
        int ec = (e + k < e1) ? e + k : e1 - 1;
        int j = __builtin_amdgcn_readfirstlane(csr_src[ec]);
        out[k] = *(const float2*)&xl[(size_t)j * HID + ch0];
    }
}

__global__ __launch_bounds__(256) void k_edge(const int* __restrict__ row_ptr,
                                              const int* __restrict__ csr_src,
                                              const float* __restrict__ csr_ea,
                                              const float* __restrict__ xl,
                                              const float* __restrict__ xr,
                                              const float* __restrict__ We_l,
                                              const float* __restrict__ att_l,
                                              float* __restrict__ gout) {
    int wave = (blockIdx.x * blockDim.x + threadIdx.x) >> 6;
    int lane = threadIdx.x & 63;
    if (wave >= N) return;
    int i = wave;
    int hh = lane >> 4;
    int ss = lane & 15;
    int ch0 = hh * 32 + 2 * ss;

    float2 xr2 = *(const float2*)&xr[(size_t)i * HID + ch0];
    float a0 = att_l[ch0], a1 = att_l[ch0 + 1];
    float we0[6], we1[6];
#pragma unroll
    for (int d = 0; d < 6; d++) {
        float2 w = *(const float2*)&We_l[d * HID + ch0];
        we0[d] = w.x;
        we1[d] = w.y;
    }

    float rm = -INFINITY, rd = 0.0f, acc0 = 0.0f, acc1 = 0.0f;

    int e0 = __builtin_amdgcn_readfirstlane(row_ptr[i]);
    int e1 = __builtin_amdgcn_readfirstlane(row_ptr[i + 1]);

    auto body = [&](int e, const float2 xlv[4]) {
        float p[4];
#pragma unroll
        for (int k = 0; k < 4; k++) {
            int ee = e + k;
            int ec = (ee < e1) ? ee : (e1 - 1);
            const float4* ea4 = (const float4*)(csr_ea + (size_t)ec * 8);
            float4 eaA = ea4[0];
            float4 eaB = ea4[1];
            float s0 = eaA.x * we0[0], s1 = eaA.x * we1[0];
            s0 = fmaf(eaA.y, we0[1], s0); s1 = fmaf(eaA.y, we1[1], s1);
            s0 = fmaf(eaA.z, we0[2], s0); s1 = fmaf(eaA.z, we1[2], s1);
            s0 = fmaf(eaA.w, we0[3], s0); s1 = fmaf(eaA.w, we1[3], s1);
            s0 = fmaf(eaB.x, we0[4], s0); s1 = fmaf(eaB.x, we1[4], s1);
            s0 = fmaf(eaB.y, we0[5], s0); s1 = fmaf(eaB.y, we1[5], s1);
            float m0 = xlv[k].x + xr2.x + s0;
            float m1 = xlv[k].y + xr2.y + s1;
            m0 = fmaxf(m0, 0.2f * m0);       // leaky relu (both signs)
            m1 = fmaxf(m1, 0.2f * m1);
            float pv = m0 * a0;
            pv = fmaf(m1, a1, pv);
            pv = red16(pv);                  // per-head score, all 16 lanes
            p[k] = (ee < e1) ? pv : -INFINITY;
        }
        float bm = fmaxf(fmaxf(p[0], p[1]), fmaxf(p[2], p[3]));
        float nm = fmaxf(rm, bm);
        float sc = __expf(rm - nm);
        rd *= sc; acc0 *= sc; acc1 *= sc;
#pragma unroll
        for (int k = 0; k < 4; k++) {
            float ek = __expf(p[k] - nm);
            rd += ek;
            acc0 = fmaf(ek, xlv[k].x, acc0);
            acc1 = fmaf(ek, xlv[k].y, acc1);
        }
        rm = nm;
    };

    float2 bufA[4], bufB[4];
    pf_xl(e0, e1, csr_src, xl, ch0, bufA);
    for (int e = e0; e < e1; e += 8) {
        pf_xl(e + 4, e1, csr_src, xl, ch0, bufB);
        body(e, bufA);
        pf_xl(e + 8, e1, csr_src, xl, ch0, bufA);
        if (e + 4 < e1) body(e + 4, bufB);
    }
    float inv = 1.0f / rd;
    float2 o = {acc0 * inv, acc1 * inv};
    *(float2*)&gout[(size_t)i * HID + ch0] = o;
}

// ---------------------------------------------------------------------------
// BatchNorm over nodes: stats then apply (+residual, relu) — apply only
// after odd layers; even-layer BN is fused into the next k_gemm_lr.
// ---------------------------------------------------------------------------
__global__ __launch_bounds__(256) void k_bnstats(const float* __restrict__ v,
                                                 float* __restrict__ sums) {
    __shared__ float l_s[256], l_q[256];
    int t = threadIdx.x;
    int c = t & 127;
    int half = t >> 7;
    int r = blockIdx.x * 64 + half;
    float s = 0.0f, q = 0.0f;
    for (int it = 0; it < 32; it++, r += 2) {
        float val = v[(size_t)r * HID + c];
        s += val;
        q += val * val;
    }
    l_s[t] = s; l_q[t] = q;
    __syncthreads();
    if (t < 128) {
        s = l_s[t] + l_s[t + 128];
        q = l_q[t] + l_q[t + 128];
        atomicAdd(&sums[c], s);
        atomicAdd(&sums[128 + c], q);
    }
}

__global__ __launch_bounds__(256) void k_bnapply(const float* __restrict__ g,
                                                 const float* __restrict__ sums,
                                                 const float* __restrict__ gamma,
                                                 const float* __restrict__ beta,
                                                 const float* __restrict__ res,
                                                 float* __restrict__ out) {
    int idx4 = (blockIdx.x * 256 + threadIdx.x) * 4;
    int c = idx4 & 127;
    const float invN = 1.0f / (float)N;
    float4 gv = *(const float4*)&g[idx4];
    float4 s4 = *(const float4*)&sums[c];
    float4 q4 = *(const float4*)&sums[128 + c];
    float4 gm = *(const float4*)&gamma[c];
    float4 bt = *(const float4*)&beta[c];
    float4 o;
    {
        float mean = s4.x * invN, var = q4.x * invN - mean * mean;
        o.x = gm.x * (gv.x - mean) * rsqrtf(var + 1e-5f) + bt.x;
        mean = s4.y * invN; var = q4.y * invN - mean * mean;
        o.y = gm.y * (gv.y - mean) * rsqrtf(var + 1e-5f) + bt.y;
        mean = s4.z * invN; var = q4.z * invN - mean * mean;
        o.z = gm.z * (gv.z - mean) * rsqrtf(var + 1e-5f) + bt.z;
        mean = s4.w * invN; var = q4.w * invN - mean * mean;
        o.w = gm.w * (gv.w - mean) * rsqrtf(var + 1e-5f) + bt.w;
    }
    float4 r4 = *(const float4*)&res[idx4];
    o.x = fmaxf(o.x + r4.x, 0.0f);
    o.y = fmaxf(o.y + r4.y, 0.0f);
    o.z = fmaxf(o.z + r4.z, 0.0f);
    o.w = fmaxf(o.w + r4.w, 0.0f);
    *(float4*)&out[idx4] = o;
}

// ---------------------------------------------------------------------------
// Pool per graph (batch is sorted) + MLP head
// ---------------------------------------------------------------------------
__global__ __launch_bounds__(128) void k_pool(const float* __restrict__ h,
                                              const int* __restrict__ batch,
                                              const float* __restrict__ W1,
                                              const float* __restrict__ b1,
                                              const float* __restrict__ W2,
                                              const float* __restrict__ b2,
                                              float* __restrict__ out) {
    __shared__ float pooled[HID];
    __shared__ float hid[64];
    __shared__ int bounds[2];
    int g = blockIdx.x;
    int t = threadIdx.x;
    if (t < 2) {
        int target = g + t;
        int lo = 0, hi = N;
        while (lo < hi) {
            int mid = (lo + hi) >> 1;
            if (batch[mid] < target) lo = mid + 1; else hi = mid;
        }
        bounds[t] = lo;
    }
    __syncthreads();
    int s = bounds[0], e = bounds[1];
    float acc = 0.0f;
    for (int r = s; r < e; r++) acc += h[(size_t)r * HID + t];
    float cntf = fmaxf((float)(e - s), 1.0f);
    pooled[t] = acc / cntf;
    __syncthreads();
    if (t < 64) {
        float a = b1[t];
#pragma unroll 4
        for (int c = 0; c < HID; c++) a += pooled[c] * W1[c * 64 + t];
        hid[t] = fmaxf(a, 0.0f);
    }
    __syncthreads();
    if (t < 3) {
        float a = b2[t];
#pragma unroll
        for (int j = 0; j < 64; j++) a += hid[j] * W2[j * 3 + t];
        out[g * 3 + t] = a;
    }
}

// ---------------------------------------------------------------------------
// Launch
// ---------------------------------------------------------------------------
extern "C" void kernel_launch(void* const* d_in, const int* in_sizes, int n_in,
                              void* d_out, int out_size, void* d_ws, size_t ws_size,
                              hipStream_t stream) {
    const float* x         = (const float*)d_in[0];
    const int*   edge_index= (const int*)d_in[1];
    const float* edge_attr = (const float*)d_in[2];
    const int*   batch     = (const int*)d_in[3];
    const float* Win       = (const float*)d_in[4];
    const float* b_in      = (const float*)d_in[5];
    const float* Wl        = (const float*)d_in[6];
    const float* bl        = (const float*)d_in[7];
    const float* Wr        = (const float*)d_in[8];
    const float* br        = (const float*)d_in[9];
    const float* We        = (const float*)d_in[10];
    const float* att       = (const float*)d_in[11];
    const float* gamma     = (const float*)d_in[13];
    const float* beta      = (const float*)d_in[14];
    const float* W1        = (const float*)d_in[15];
    const float* b1        = (const float*)d_in[16];
    const float* W2        = (const float*)d_in[17];
    const float* b2        = (const float*)d_in[18];
    float* out = (float*)d_out;

    const int* src0 = edge_index;
    const int* dst0 = edge_index + E;

    char* ws = (char*)d_ws;
    size_t off = 0;
    auto alloc = [&](size_t bytes) -> void* {
        void* p = ws + off;
        off += (bytes + 255) & ~(size_t)255;
        return p;
    };
    // cnt+fill, bnsums, loopsum contiguous: one memset covers all.
    int*   cnt       = (int*)alloc((size_t)2 * N * sizeof(int));
    int*   fill      = cnt + N;
    float* bnsums    = (float*)alloc((size_t)8 * 256 * sizeof(float));
    float* loopsum   = (float*)alloc((size_t)N * 6 * sizeof(float));
    int*   row_ptr   = (int*)alloc((size_t)(N + 1) * sizeof(int));
    int*   csr_src   = (int*)alloc((size_t)EF * sizeof(int));
    int*   csr_eid   = (int*)alloc((size_t)EF * sizeof(int));
    float* csr_ea    = (float*)alloc((size_t)EF * 8 * sizeof(float));
    float* H0        = (float*)alloc((size_t)N * HID * sizeof(float));
    float* XL        = (float*)alloc((size_t)N * HID * sizeof(float));
    float* XR        = (float*)alloc((size_t)N * HID * sizeof(float));
    float* GOUT      = (float*)alloc((size_t)N * HID * sizeof(float));

    size_t zbytes = (size_t)2 * N * sizeof(int) + 8 * 256 * sizeof(float)
                  + (size_t)N * 6 * sizeof(float);
    hipMemsetAsync(cnt, 0, zbytes, stream);
    k_hist<<<(E + 255) / 256, 256, 0, stream>>>(dst0, edge_attr, cnt, loopsum);
    k_scan<<<1, 1024, 0, stream>>>(cnt, row_ptr);
    k_scatter<<<(E + 255) / 256, 256, 0, stream>>>(src0, dst0, row_ptr, fill,
                                                   csr_src, csr_eid);
    k_selfloop<<<(N + 255) / 256, 256, 0, stream>>>(row_ptr, csr_src, csr_eid);
    k_build_ea<<<(EF + 255) / 256, 256, 0, stream>>>(csr_eid, row_ptr, edge_attr,
                                                     loopsum, csr_ea);
    k_ingemm<<<N, 128, 0, stream>>>(x, Win, b_in, H0);

    for (int l = 0; l < 8; l++) {
        bool odd = (l & 1) != 0;
        const float* hin = odd ? GOUT : H0;
        const float* bns_in = odd ? (bnsums + (l - 1) * 256) : nullptr;
        const float* g_in  = odd ? (gamma + (l - 1) * HID) : nullptr;
        const float* b_in2 = odd ? (beta  + (l - 1) * HID) : nullptr;
        k_gemm_lr<<<N / 16, 256, 0, stream>>>(hin, bns_in, g_in, b_in2,
                                              Wl + (size_t)l * HID * HID, bl + l * HID,
                                              Wr + (size_t)l * HID * HID, br + l * HID,
                                              XL, XR);
        k_edge<<<N / 4, 256, 0, stream>>>(row_ptr, csr_src, csr_ea,
                                          XL, XR,
                                          We + (size_t)l * 6 * HID,
                                          att + (size_t)l * HID, GOUT);
        float* bns = bnsums + l * 256;
        k_bnstats<<<256, 256, 0, stream>>>(GOUT, bns);
        if (odd) {
            k_bnapply<<<(N * HID) / 1024, 256, 0, stream>>>(GOUT, bns,
                                                            gamma + l * HID,
                                                            beta + l * HID,
                                                            H0, H0);
        }
    }
    k_pool<<<G, 128, 0, stream>>>(H0, batch, W1, b1, W2, b2, out);
}

// Round 4
// 759.270 us; speedup vs baseline: 1.1452x; 1.1452x over previous
//
#include <hip/hip_runtime.h>
#include <math.h>

// Problem constants (match reference)
constexpr int N   = 16384;
constexpr int E   = 393216;
constexpr int EF  = E + N;     // edges + self loops
constexpr int G   = 256;
constexpr int HID = 128;

// ---------------------------------------------------------------------------
// 16-lane (DPP row) all-lanes sum via row_ror 1,2,4,8 — pure VALU
// ---------------------------------------------------------------------------
__device__ __forceinline__ float red16(float x) {
    union fi { float f; int i; };
    fi a, b;
    a.f = x;
    b.i = __builtin_amdgcn_mov_dpp(a.i, 0x121, 0xf, 0xf, false); a.f += b.f;
    b.i = __builtin_amdgcn_mov_dpp(a.i, 0x122, 0xf, 0xf, false); a.f += b.f;
    b.i = __builtin_amdgcn_mov_dpp(a.i, 0x124, 0xf, 0xf, false); a.f += b.f;
    b.i = __builtin_amdgcn_mov_dpp(a.i, 0x128, 0xf, 0xf, false); a.f += b.f;
    return a.f;
}

// ---------------------------------------------------------------------------
// Preprocessing: CSR by destination (count-only hist — float atomics were a
// 100 µs regression in R3; loop_attr mean is computed later from csr_ea).
// ---------------------------------------------------------------------------
__global__ __launch_bounds__(256) void k_hist(const int* __restrict__ dst,
                                              int* __restrict__ cnt) {
    int e = blockIdx.x * 256 + threadIdx.x;
    if (e < E) atomicAdd(&cnt[dst[e]], 1);
}

// single-block inclusive scan over N=16384 = 1024*16 counts (+1 self loop each)
__global__ __launch_bounds__(1024) void k_scan(const int* __restrict__ cnt,
                                               int* __restrict__ row_ptr) {
    __shared__ int lds[1024];
    int t = threadIdx.x;
    int local[16];
    int s = 0;
    int base = t * 16;
#pragma unroll
    for (int q = 0; q < 16; q++) { local[q] = cnt[base + q] + 1; s += local[q]; }
    lds[t] = s;
    __syncthreads();
    for (int off = 1; off < 1024; off <<= 1) {
        int v = (t >= off) ? lds[t - off] : 0;
        __syncthreads();
        lds[t] += v;
        __syncthreads();
    }
    int run = (t == 0) ? 0 : lds[t - 1];
    if (t == 0) row_ptr[0] = 0;
#pragma unroll
    for (int q = 0; q < 16; q++) { run += local[q]; row_ptr[base + q + 1] = run; }
}

__global__ __launch_bounds__(256) void k_scatter(const int* __restrict__ src,
                                                 const int* __restrict__ dst,
                                                 const int* __restrict__ row_ptr,
                                                 int* __restrict__ fill,
                                                 int* __restrict__ csr_src,
                                                 int* __restrict__ csr_eid) {
    int e = blockIdx.x * 256 + threadIdx.x;
    if (e >= E) return;
    int d = dst[e];
    int pos = row_ptr[d] + atomicAdd(&fill[d], 1);
    csr_src[pos] = src[e];
    csr_eid[pos] = e;
}

__global__ __launch_bounds__(256) void k_selfloop(const int* __restrict__ row_ptr,
                                                  int* __restrict__ csr_src,
                                                  int* __restrict__ csr_eid) {
    int i = blockIdx.x * 256 + threadIdx.x;
    if (i >= N) return;
    int pos = row_ptr[i + 1] - 1;   // last slot of row i is the self loop
    csr_src[pos] = i;
    csr_eid[pos] = E + i;
}

// Gather edge_attr into CSR slot order (real edges only), pad to 8 floats.
__global__ __launch_bounds__(256) void k_build_ea(const int* __restrict__ csr_eid,
                                                  const float* __restrict__ edge_attr,
                                                  float* __restrict__ csr_ea) {
    int p = blockIdx.x * 256 + threadIdx.x;
    if (p >= EF) return;
    int eid = csr_eid[p];
    if (eid >= E) return;          // self-loop slot: filled by k_loopattr2
    const float* s = edge_attr + (size_t)eid * 6;
    float4 a = {s[0], s[1], s[2], s[3]};
    float4 b = {s[4], s[5], 0.0f, 0.0f};
    float4* dst = (float4*)(csr_ea + (size_t)p * 8);
    dst[0] = a;
    dst[1] = b;
}

// Self-loop attr = mean of the row's real-edge attrs, computed from the
// already-gathered contiguous csr_ea records; written into the last slot.
__global__ __launch_bounds__(256) void k_loopattr2(const int* __restrict__ row_ptr,
                                                   float* __restrict__ csr_ea) {
    int i = blockIdx.x * 256 + threadIdx.x;
    if (i >= N) return;
    int e0 = row_ptr[i], e1 = row_ptr[i + 1] - 1;   // e1 = self-loop slot
    float4 sa = {0, 0, 0, 0};
    float sbx = 0.0f, sby = 0.0f;
    for (int e = e0; e < e1; e++) {
        const float4* p = (const float4*)(csr_ea + (size_t)e * 8);
        float4 a = p[0];
        float4 b = p[1];
        sa.x += a.x; sa.y += a.y; sa.z += a.z; sa.w += a.w;
        sbx += b.x; sby += b.y;
    }
    float inv = 1.0f / fmaxf((float)(e1 - e0), 1.0f);
    float4 oa = {sa.x * inv, sa.y * inv, sa.z * inv, sa.w * inv};
    float4 ob = {sbx * inv, sby * inv, 0.0f, 0.0f};
    float4* q = (float4*)(csr_ea + (size_t)e1 * 8);
    q[0] = oa;
    q[1] = ob;
}

// ---------------------------------------------------------------------------
// Input projection: h = relu(x @ Win + b_in), x is (N,21)
// ---------------------------------------------------------------------------
__global__ __launch_bounds__(128) void k_ingemm(const float* __restrict__ x,
                                                const float* __restrict__ Win,
                                                const float* __restrict__ b_in,
                                                float* __restrict__ h) {
    __shared__ float xs[21];
    int i = blockIdx.x;
    int c = threadIdx.x;
    if (c < 21) xs[c] = x[i * 21 + c];
    __syncthreads();
    float acc = b_in[c];
#pragma unroll
    for (int d = 0; d < 21; d++) acc += xs[d] * Win[d * HID + c];
    h[i * HID + c] = fmaxf(acc, 0.0f);
}

// ---------------------------------------------------------------------------
// Per-layer projections: XL = h@Wl + bl, XR = h@Wr + br
// 16-row tile per block; thread owns (matrix, col-pair, 8 rows).
// If bns != nullptr the input is GOUT of the previous (even) layer and
// relu(BN(.)) is applied on the fly during the tile load.
// ---------------------------------------------------------------------------
__global__ __launch_bounds__(256) void k_gemm_lr(const float* __restrict__ h,
                                                 const float* __restrict__ bns,
                                                 const float* __restrict__ gamma,
                                                 const float* __restrict__ beta,
                                                 const float* __restrict__ Wl,
                                                 const float* __restrict__ bl,
                                                 const float* __restrict__ Wr,
                                                 const float* __restrict__ br,
                                                 float* __restrict__ XL,
                                                 float* __restrict__ XR) {
    __shared__ float hs[16][HID];
    __shared__ float sc[HID], sh[HID];
    int t = threadIdx.x;
    int r0 = blockIdx.x * 16;
    if (bns) {
        if (t < 128) {
            const float invN = 1.0f / (float)N;
            float mean = bns[t] * invN;
            float var  = bns[128 + t] * invN - mean * mean;
            float inv  = rsqrtf(var + 1e-5f);
            float s = gamma[t] * inv;
            sc[t] = s;
            sh[t] = beta[t] - mean * s;
        }
        __syncthreads();
    }
    {
        int row = t >> 4;
        int col = (t & 15) * 8;
        const float4* src = (const float4*)&h[(size_t)(r0 + row) * HID + col];
        float4 a = src[0];
        float4 b = src[1];
        if (bns) {
            float4 s0 = *(const float4*)&sc[col];
            float4 s1 = *(const float4*)&sc[col + 4];
            float4 h0 = *(const float4*)&sh[col];
            float4 h1 = *(const float4*)&sh[col + 4];
            a.x = fmaxf(fmaf(a.x, s0.x, h0.x), 0.0f);
            a.y = fmaxf(fmaf(a.y, s0.y, h0.y), 0.0f);
            a.z = fmaxf(fmaf(a.z, s0.z, h0.z), 0.0f);
            a.w = fmaxf(fmaf(a.w, s0.w, h0.w), 0.0f);
            b.x = fmaxf(fmaf(b.x, s1.x, h1.x), 0.0f);
            b.y = fmaxf(fmaf(b.y, s1.y, h1.y), 0.0f);
            b.z = fmaxf(fmaf(b.z, s1.z, h1.z), 0.0f);
            b.w = fmaxf(fmaf(b.w, s1.w, h1.w), 0.0f);
        }
        float4* dst = (float4*)&hs[row][col];
        dst[0] = a;
        dst[1] = b;
    }
    __syncthreads();
    bool right = t >= 128;
    int cp = (t & 63) * 2;
    int rbase = ((t >> 6) & 1) * 8;
    const float* W    = right ? Wr : Wl;
    const float* bias = right ? br : bl;
    float* OUT        = right ? XR : XL;
    float b0 = bias[cp], b1 = bias[cp + 1];
    float acc0[8], acc1[8];
#pragma unroll
    for (int r = 0; r < 8; r++) { acc0[r] = b0; acc1[r] = b1; }
    for (int k = 0; k < HID; k += 4) {
        float4 h4[8];
#pragma unroll
        for (int r = 0; r < 8; r++) h4[r] = *(const float4*)&hs[rbase + r][k];
#pragma unroll
        for (int kk = 0; kk < 4; kk++) {
            float2 w = *(const float2*)&W[(size_t)(k + kk) * HID + cp];
#pragma unroll
            for (int r = 0; r < 8; r++) {
                float hv = ((const float*)&h4[r])[kk];
                acc0[r] = fmaf(hv, w.x, acc0[r]);
                acc1[r] = fmaf(hv, w.y, acc1[r]);
            }
        }
    }
#pragma unroll
    for (int r = 0; r < 8; r++) {
        float2 o = {acc0[r], acc1[r]};
        *(float2*)&OUT[(size_t)(r0 + rbase + r) * HID + cp] = o;
    }
}

// ---------------------------------------------------------------------------
// Edge kernel: one wave per node. Lane = head*16 + s; owns channels
// (h*32+2s, h*32+2s+1). 4-step DPP row reduction for the attention dot;
// 4-edge-batched online softmax, xl gathers prefetched one chunk ahead.
// ---------------------------------------------------------------------------
__device__ __forceinline__ void pf_xl(int e, int e1,
                                      const int* __restrict__ csr_src,
                                      const float* __restrict__ xl, int ch0,
                                      float2 out[4]) {
#pragma unroll
    for (int k = 0; k < 4; k++) {
        int ec = (e + k < e1) ? e + k : e1 - 1;
        int j = __builtin_amdgcn_readfirstlane(csr_src[ec]);
        out[k] = *(const float2*)&xl[(size_t)j * HID + ch0];
    }
}

__global__ __launch_bounds__(256) void k_edge(const int* __restrict__ row_ptr,
                                              const int* __restrict__ csr_src,
                                              const float* __restrict__ csr_ea,
                                              const float* __restrict__ xl,
                                              const float* __restrict__ xr,
                                              const float* __restrict__ We_l,
                                              const float* __restrict__ att_l,
                                              float* __restrict__ gout) {
    int wave = (blockIdx.x * blockDim.x + threadIdx.x) >> 6;
    int lane = threadIdx.x & 63;
    if (wave >= N) return;
    int i = wave;
    int hh = lane >> 4;
    int ss = lane & 15;
    int ch0 = hh * 32 + 2 * ss;

    float2 xr2 = *(const float2*)&xr[(size_t)i * HID + ch0];
    float a0 = att_l[ch0], a1 = att_l[ch0 + 1];
    float we0[6], we1[6];
#pragma unroll
    for (int d = 0; d < 6; d++) {
        float2 w = *(const float2*)&We_l[d * HID + ch0];
        we0[d] = w.x;
        we1[d] = w.y;
    }

    float rm = -INFINITY, rd = 0.0f, acc0 = 0.0f, acc1 = 0.0f;

    int e0 = __builtin_amdgcn_readfirstlane(row_ptr[i]);
    int e1 = __builtin_amdgcn_readfirstlane(row_ptr[i + 1]);

    auto body = [&](int e, const float2 xlv[4]) {
        float p[4];
#pragma unroll
        for (int k = 0; k < 4; k++) {
            int ee = e + k;
            int ec = (ee < e1) ? ee : (e1 - 1);
            const float4* ea4 = (const float4*)(csr_ea + (size_t)ec * 8);
            float4 eaA = ea4[0];
            float4 eaB = ea4[1];
            float s0 = eaA.x * we0[0], s1 = eaA.x * we1[0];
            s0 = fmaf(eaA.y, we0[1], s0); s1 = fmaf(eaA.y, we1[1], s1);
            s0 = fmaf(eaA.z, we0[2], s0); s1 = fmaf(eaA.z, we1[2], s1);
            s0 = fmaf(eaA.w, we0[3], s0); s1 = fmaf(eaA.w, we1[3], s1);
            s0 = fmaf(eaB.x, we0[4], s0); s1 = fmaf(eaB.x, we1[4], s1);
            s0 = fmaf(eaB.y, we0[5], s0); s1 = fmaf(eaB.y, we1[5], s1);
            float m0 = xlv[k].x + xr2.x + s0;
            float m1 = xlv[k].y + xr2.y + s1;
            m0 = fmaxf(m0, 0.2f * m0);       // leaky relu (both signs)
            m1 = fmaxf(m1, 0.2f * m1);
            float pv = m0 * a0;
            pv = fmaf(m1, a1, pv);
            pv = red16(pv);                  // per-head score, all 16 lanes
            p[k] = (ee < e1) ? pv : -INFINITY;
        }
        float bm = fmaxf(fmaxf(p[0], p[1]), fmaxf(p[2], p[3]));
        float nm = fmaxf(rm, bm);
        float sc = __expf(rm - nm);
        rd *= sc; acc0 *= sc; acc1 *= sc;
#pragma unroll
        for (int k = 0; k < 4; k++) {
            float ek = __expf(p[k] - nm);
            rd += ek;
            acc0 = fmaf(ek, xlv[k].x, acc0);
            acc1 = fmaf(ek, xlv[k].y, acc1);
        }
        rm = nm;
    };

    float2 bufA[4], bufB[4];
    pf_xl(e0, e1, csr_src, xl, ch0, bufA);
    for (int e = e0; e < e1; e += 8) {
        pf_xl(e + 4, e1, csr_src, xl, ch0, bufB);
        body(e, bufA);
        pf_xl(e + 8, e1, csr_src, xl, ch0, bufA);
        if (e + 4 < e1) body(e + 4, bufB);
    }
    float inv = 1.0f / rd;
    float2 o = {acc0 * inv, acc1 * inv};
    *(float2*)&gout[(size_t)i * HID + ch0] = o;
}

// ---------------------------------------------------------------------------
// BatchNorm over nodes: stats then apply (+residual, relu) — apply only
// after odd layers; even-layer BN is fused into the next k_gemm_lr.
// ---------------------------------------------------------------------------
__global__ __launch_bounds__(256) void k_bnstats(const float* __restrict__ v,
                                                 float* __restrict__ sums) {
    __shared__ float l_s[256], l_q[256];
    int t = threadIdx.x;
    int c = t & 127;
    int half = t >> 7;
    int r = blockIdx.x * 64 + half;
    float s = 0.0f, q = 0.0f;
    for (int it = 0; it < 32; it++, r += 2) {
        float val = v[(size_t)r * HID + c];
        s += val;
        q += val * val;
    }
    l_s[t] = s; l_q[t] = q;
    __syncthreads();
    if (t < 128) {
        s = l_s[t] + l_s[t + 128];
        q = l_q[t] + l_q[t + 128];
        atomicAdd(&sums[c], s);
        atomicAdd(&sums[128 + c], q);
    }
}

__global__ __launch_bounds__(256) void k_bnapply(const float* __restrict__ g,
                                                 const float* __restrict__ sums,
                                                 const float* __restrict__ gamma,
                                                 const float* __restrict__ beta,
                                                 const float* __restrict__ res,
                                                 float* __restrict__ out) {
    int idx4 = (blockIdx.x * 256 + threadIdx.x) * 4;
    int c = idx4 & 127;
    const float invN = 1.0f / (float)N;
    float4 gv = *(const float4*)&g[idx4];
    float4 s4 = *(const float4*)&sums[c];
    float4 q4 = *(const float4*)&sums[128 + c];
    float4 gm = *(const float4*)&gamma[c];
    float4 bt = *(const float4*)&beta[c];
    float4 o;
    {
        float mean = s4.x * invN, var = q4.x * invN - mean * mean;
        o.x = gm.x * (gv.x - mean) * rsqrtf(var + 1e-5f) + bt.x;
        mean = s4.y * invN; var = q4.y * invN - mean * mean;
        o.y = gm.y * (gv.y - mean) * rsqrtf(var + 1e-5f) + bt.y;
        mean = s4.z * invN; var = q4.z * invN - mean * mean;
        o.z = gm.z * (gv.z - mean) * rsqrtf(var + 1e-5f) + bt.z;
        mean = s4.w * invN; var = q4.w * invN - mean * mean;
        o.w = gm.w * (gv.w - mean) * rsqrtf(var + 1e-5f) + bt.w;
    }
    float4 r4 = *(const float4*)&res[idx4];
    o.x = fmaxf(o.x + r4.x, 0.0f);
    o.y = fmaxf(o.y + r4.y, 0.0f);
    o.z = fmaxf(o.z + r4.z, 0.0f);
    o.w = fmaxf(o.w + r4.w, 0.0f);
    *(float4*)&out[idx4] = o;
}

// ---------------------------------------------------------------------------
// Pool per graph (batch is sorted) + MLP head
// ---------------------------------------------------------------------------
__global__ __launch_bounds__(128) void k_pool(const float* __restrict__ h,
                                              const int* __restrict__ batch,
                                              const float* __restrict__ W1,
                                              const float* __restrict__ b1,
                                              const float* __restrict__ W2,
                                              const float* __restrict__ b2,
                                              float* __restrict__ out) {
    __shared__ float pooled[HID];
    __shared__ float hid[64];
    __shared__ int bounds[2];
    int g = blockIdx.x;
    int t = threadIdx.x;
    if (t < 2) {
        int target = g + t;
        int lo = 0, hi = N;
        while (lo < hi) {
            int mid = (lo + hi) >> 1;
            if (batch[mid] < target) lo = mid + 1; else hi = mid;
        }
        bounds[t] = lo;
    }
    __syncthreads();
    int s = bounds[0], e = bounds[1];
    float acc = 0.0f;
    for (int r = s; r < e; r++) acc += h[(size_t)r * HID + t];
    float cntf = fmaxf((float)(e - s), 1.0f);
    pooled[t] = acc / cntf;
    __syncthreads();
    if (t < 64) {
        float a = b1[t];
#pragma unroll 4
        for (int c = 0; c < HID; c++) a += pooled[c] * W1[c * 64 + t];
        hid[t] = fmaxf(a, 0.0f);
    }
    __syncthreads();
    if (t < 3) {
        float a = b2[t];
#pragma unroll
        for (int j = 0; j < 64; j++) a += hid[j] * W2[j * 3 + t];
        out[g * 3 + t] = a;
    }
}

// ---------------------------------------------------------------------------
// Launch
// ---------------------------------------------------------------------------
extern "C" void kernel_launch(void* const* d_in, const int* in_sizes, int n_in,
                              void* d_out, int out_size, void* d_ws, size_t ws_size,
                              hipStream_t stream) {
    const float* x         = (const float*)d_in[0];
    const int*   edge_index= (const int*)d_in[1];
    const float* edge_attr = (const float*)d_in[2];
    const int*   batch     = (const int*)d_in[3];
    const float* Win       = (const float*)d_in[4];
    const float* b_in      = (const float*)d_in[5];
    const float* Wl        = (const float*)d_in[6];
    const float* bl        = (const float*)d_in[7];
    const float* Wr        = (const float*)d_in[8];
    const float* br        = (const float*)d_in[9];
    const float* We        = (const float*)d_in[10];
    const float* att       = (const float*)d_in[11];
    const float* gamma     = (const float*)d_in[13];
    const float* beta      = (const float*)d_in[14];
    const float* W1        = (const float*)d_in[15];
    const float* b1        = (const float*)d_in[16];
    const float* W2        = (const float*)d_in[17];
    const float* b2        = (const float*)d_in[18];
    float* out = (float*)d_out;

    const int* src0 = edge_index;
    const int* dst0 = edge_index + E;

    char* ws = (char*)d_ws;
    size_t off = 0;
    auto alloc = [&](size_t bytes) -> void* {
        void* p = ws + off;
        off += (bytes + 255) & ~(size_t)255;
        return p;
    };
    // cnt+fill and bnsums contiguous: one memset covers all.
    int*   cnt       = (int*)alloc((size_t)2 * N * sizeof(int));
    int*   fill      = cnt + N;
    float* bnsums    = (float*)alloc((size_t)8 * 256 * sizeof(float));
    int*   row_ptr   = (int*)alloc((size_t)(N + 1) * sizeof(int));
    int*   csr_src   = (int*)alloc((size_t)EF * sizeof(int));
    int*   csr_eid   = (int*)alloc((size_t)EF * sizeof(int));
    float* csr_ea    = (float*)alloc((size_t)EF * 8 * sizeof(float));
    float* H0        = (float*)alloc((size_t)N * HID * sizeof(float));
    float* XL        = (float*)alloc((size_t)N * HID * sizeof(float));
    float* XR        = (float*)alloc((size_t)N * HID * sizeof(float));
    float* GOUT      = (float*)alloc((size_t)N * HID * sizeof(float));

    size_t zbytes = (size_t)2 * N * sizeof(int) + 8 * 256 * sizeof(float);
    hipMemsetAsync(cnt, 0, zbytes, stream);
    k_hist<<<(E + 255) / 256, 256, 0, stream>>>(dst0, cnt);
    k_scan<<<1, 1024, 0, stream>>>(cnt, row_ptr);
    k_scatter<<<(E + 255) / 256, 256, 0, stream>>>(src0, dst0, row_ptr, fill,
                                                   csr_src, csr_eid);
    k_selfloop<<<(N + 255) / 256, 256, 0, stream>>>(row_ptr, csr_src, csr_eid);
    k_build_ea<<<(EF + 255) / 256, 256, 0, stream>>>(csr_eid, edge_attr, csr_ea);
    k_loopattr2<<<(N + 255) / 256, 256, 0, stream>>>(row_ptr, csr_ea);
    k_ingemm<<<N, 128, 0, stream>>>(x, Win, b_in, H0);

    for (int l = 0; l < 8; l++) {
        bool odd = (l & 1) != 0;
        const float* hin = odd ? GOUT : H0;
        const float* bns_in = odd ? (bnsums + (l - 1) * 256) : nullptr;
        const float* g_in  = odd ? (gamma + (l - 1) * HID) : nullptr;
        const float* b_in2 = odd ? (beta  + (l - 1) * HID) : nullptr;
        k_gemm_lr<<<N / 16, 256, 0, stream>>>(hin, bns_in, g_in, b_in2,
                                              Wl + (size_t)l * HID * HID, bl + l * HID,
                                              Wr + (size_t)l * HID * HID, br + l * HID,
                                              XL, XR);
        k_edge<<<N / 4, 256, 0, stream>>>(row_ptr, csr_src, csr_ea,
                                          XL, XR,
                                          We + (size_t)l * 6 * HID,
                                          att + (size_t)l * HID, GOUT);
        float* bns = bnsums + l * 256;
        k_bnstats<<<256, 256, 0, stream>>>(GOUT, bns);
        if (odd) {
            k_bnapply<<<(N * HID) / 1024, 256, 0, stream>>>(GOUT, bns,
                                                            gamma + l * HID,
                                                            beta + l * HID,
                                                            H0, H0);
        }
    }
    k_pool<<<G, 128, 0, stream>>>(H0, batch, W1, b1, W2, b2, out);
}